// Round 9
// baseline (179.944 us; speedup 1.0000x reference)
//
#include <hip/hip_runtime.h>

typedef _Float16 half_t;
typedef _Float16 half8 __attribute__((ext_vector_type(8)));
typedef _Float16 half4 __attribute__((ext_vector_type(4)));
typedef float f32x4 __attribute__((ext_vector_type(4)));

#define MFMA32(a, b, c) __builtin_amdgcn_mfma_f32_16x16x32_f16((a), (b), (c), 0, 0, 0)
#define MFMA16(a, b, c) __builtin_amdgcn_mfma_f32_16x16x16f16((a), (b), (c), 0, 0, 0)

static constexpr int kM  = 512;
static constexpr int kD  = 64;
static constexpr int kKL = 2560;
static constexpr int kL  = 2048;
// ws (halves): q_scaled | K [bh][k][d] | Vc chunked [bh][80][64][32] | peT [l][d] | z (f32)
static constexpr int WS_QS  = 0;                    // 1,048,576
static constexpr int WS_KB  = 1048576;              // 5,242,880
static constexpr int WS_VC  = WS_KB + 5242880;      // 5,242,880
static constexpr int WS_PET = WS_VC + 5242880;      // 131,072
static constexpr int WS_Z   = WS_PET + 131072;      // 2*16384 f32

// ---------- K1: q/k convert + V chunked-transpose + pe transpose + zero out/z ----------
__global__ __launch_bounds__(256) void prep_kernel(const float* __restrict__ q,
    const float* __restrict__ k, const float* __restrict__ v,
    const float* __restrict__ pe, half_t* __restrict__ ws, float* __restrict__ out) {
  __shared__ float ls[64 * 72];
  const int b = blockIdx.x, t = threadIdx.x;
  if (b < 3072) {
    const int i = b * 256 + t;
    const float QS = 0.125f * 1.4426950408889634f;  // 1/sqrt(64) * log2(e)
    const float* src; half_t* dst; float sc;
    if (i < 131072) { src = q + (size_t)i * 8; dst = ws + WS_QS + (size_t)i * 8; sc = QS; }
    else { const int j = i - 131072; src = k + (size_t)j * 8; dst = ws + WS_KB + (size_t)j * 8; sc = 1.0f; }
    const float4 a = ((const float4*)src)[0];
    const float4 bb = ((const float4*)src)[1];
    half_t tt[8];
    tt[0] = (half_t)(a.x * sc);  tt[1] = (half_t)(a.y * sc);
    tt[2] = (half_t)(a.z * sc);  tt[3] = (half_t)(a.w * sc);
    tt[4] = (half_t)(bb.x * sc); tt[5] = (half_t)(bb.y * sc);
    tt[6] = (half_t)(bb.z * sc); tt[7] = (half_t)(bb.w * sc);
    *(int4*)dst = *(int4*)tt;
    return;
  }
  if (b >= 4384) {
    if (b < 4640) {                       // zero d_out
      float4* o = (float4*)out;
      const int base = (b - 4384) * 1024 + t;
#pragma unroll
      for (int u = 0; u < 4; ++u) o[base + u * 256] = float4{0, 0, 0, 0};
    } else {                              // zero z
      float4* z = (float4*)((float*)(ws + WS_Z));
      const int base = (b - 4640) * 1024 + t;
#pragma unroll
      for (int u = 0; u < 4; ++u) z[base + u * 256] = float4{0, 0, 0, 0};
    }
    return;
  }
  const bool isV = (b < 4352);
  int bh = 0, kt = 0, b3 = 0;
  const float* src; int sstride;
  if (isV) {
    const int b2 = b - 3072;
    bh = b2 / 40; kt = b2 % 40;
    src = v + (size_t)(bh * 2560 + kt * 64) * 64; sstride = 64;
  } else {
    b3 = b - 4352;
    src = pe + (size_t)b3 * 64; sstride = 2048;
  }
  const int rr = t >> 4, cq = (t & 15) * 4;
#pragma unroll
  for (int p = 0; p < 4; ++p) {
    const float4 x = *(const float4*)(src + (size_t)(p * 16 + rr) * sstride + cq);
    *(float4*)(ls + (p * 16 + rr) * 72 + cq) = x;
  }
  __syncthreads();
  const int oc = t >> 2, ch = t & 3;
  half_t tmp[16];
#pragma unroll
  for (int i2 = 0; i2 < 16; ++i2) tmp[i2] = (half_t)ls[(ch * 16 + i2) * 72 + oc];
  half_t* o;
  if (isV) {
    o = ws + WS_VC + (size_t)bh * 163840 + ((kt << 1) + (ch >> 1)) * 2048 + oc * 32 + ((ch & 1) << 4);
  } else {
    o = ws + WS_PET + ((size_t)b3 * 64 + oc) * 64 + ch * 16;
  }
  ((int4*)o)[0] = ((int4*)tmp)[0];
  ((int4*)o)[1] = ((int4*)tmp)[1];
}

// ---------- K2: fat-wave split-K attention, bias pipelined one step ahead ----------
// grid 512 = 32bh x 4 m-blocks(128 rows) x 4 K-splits; block 128 (2 waves x 64 rows).
// Step t (chunk g): S^T=K.Q^T from LDS-staged K; softmax reads bias strips
// WRITTEN AT STEP t-1; PV from LDS-staged Vc. Bias windows for t+1 computed
// AFTER the strip reads (peT from LDS ring depth 6, staged 2 chunks ahead).
// Critical chain per step: ds_read K -> 2 MFMA -> strip read -> exp -> PV.
// LDS (B): K 2x4608 @0 | Vc 2x5120 @9216 | peT 6x4608 @19456 | strips 8x3072 @47104 = 71680.
__global__ __launch_bounds__(128, 2) void attn_kernel(
    const half_t* __restrict__ ws, const float* __restrict__ cvp,
    float* __restrict__ out, float* __restrict__ zalA, float* __restrict__ zmA) {

  __shared__ __align__(16) char smem[71680];
  half_t* lsh = (half_t*)smem;

  const int tid  = threadIdx.x;
  const int lane = tid & 63;
  const int w2   = tid >> 6;
  const int c    = lane & 15;
  const int qd   = lane >> 4;

  const int id = blockIdx.x;                    // 512
  const int bh = ((id & 7) << 2) | (id >> 7);   // XCD-aware
  const int mid = (id >> 3) & 15;
  const int mb = mid & 3, sp = mid >> 2;
  const int m0 = mb << 7;                       // 128 rows per block
  const int g0 = sp * 17;                       // chunks [g0, g0+17)

  const float cvl = cvp[bh & 7] * 2048.0f - 2047.0f;  // mask = clamp((l+cvl)/64+1,0,1)

  const half_t* kb  = ws + WS_KB + (size_t)bh * (kKL * kD);
  const half_t* vcb = ws + WS_VC + (size_t)bh * (kKL * kD);
  const half_t* pet = ws + WS_PET;

  half8 bq0[4], bq1[4];
#pragma unroll
  for (int f = 0; f < 4; ++f) {
    const half_t* qrow = ws + WS_QS + (size_t)(bh * kM + m0 + 64 * w2 + 16 * f + c) * kD;
    bq0[f] = *(const half8*)(qrow + qd * 8);
    bq1[f] = *(const half8*)(qrow + 32 + qd * 8);
  }

  int4 stgK[2], stgV[2], stgP[2];
  auto issueKV = [&](int gg) {
#pragma unroll
    for (int u = 0; u < 2; ++u) {
      const int i = tid + (u << 7);
      const int r = i >> 3, seg = i & 7;
      int krow = m0 + (gg << 5) + r; if (krow > kKL - 1) krow = kKL - 1;
      stgK[u] = *(const int4*)(kb + (size_t)krow * kD + seg * 8);
      int vch = (m0 >> 5) + gg; if (vch > 79) vch = 79;
      stgV[u] = *(const int4*)(vcb + (size_t)vch * 2048 + i * 8);
    }
  };
  auto commitKV = [&](int gg) {
    const int sK = (gg & 1) * 2304;
    const int sV = 4608 + (gg & 1) * 2560;
#pragma unroll
    for (int u = 0; u < 2; ++u) {
      const int i = tid + (u << 7);
      const int r = i >> 3, seg = i & 7;
      *(int4*)(lsh + sK + r * 72 + seg * 8) = stgK[u];
      const int d = i >> 2, ks = (i & 3) * 8;
      *(int4*)(lsh + sV + d * 40 + ks) = stgV[u];
    }
  };
  auto issuePe = [&](int cg) {
#pragma unroll
    for (int u = 0; u < 2; ++u) {
      const int i = tid + (u << 7);
      const int r = i >> 3, seg = i & 7;
      int prow = (cg << 5) + r; prow = prow < 0 ? 0 : (prow > kL - 1 ? kL - 1 : prow);
      stgP[u] = *(const int4*)(pet + (size_t)prow * kD + seg * 8);
    }
  };
  auto commitPe = [&](int cg) {
    const int sP = 9728 + ((cg + 12) % 6) * 2304;
#pragma unroll
    for (int u = 0; u < 2; ++u) {
      const int i = tid + (u << 7);
      const int r = i >> 3, seg = i & 7;
      *(int4*)(lsh + sP + r * 72 + seg * 8) = stgP[u];
    }
  };
  auto peFrag = [&](int wb, half8& p0, half8& p1) {
    int l = wb + c; l = l < 0 ? 0 : (l > kL - 1 ? kL - 1 : l);
    const half_t* pp = lsh + 9728 + (((l >> 5) + 12) % 6) * 2304 + (l & 31) * 72;
    p0 = *(const half8*)(pp + qd * 8);
    p1 = *(const half8*)(pp + 32 + qd * 8);
  };
  auto stripWrite = [&](int f, int wb, const f32x4& a) {
    half_t* stf = lsh + 23552 + (w2 * 4 + f) * 1536;
#pragma unroll
    for (int reg = 0; reg < 4; ++reg)
      stf[((wb + qd * 4 + reg) & 63) * 24 + c] = (half_t)a[reg];
  };

  // ---- prime: peT ring chunks g0-4..g0+1, K/V chunk g0, strips for step 0 ----
  for (int ci = 0; ci < 6; ++ci) { issuePe(g0 - 4 + ci); commitPe(g0 - 4 + ci); }
  issueKV(g0); commitKV(g0);
  __syncthreads();
  const int bB0 = (g0 << 5) - 64 * w2;
  for (int k6 = 0; k6 < 6; ++k6) {
    const int wb = bB0 + 16 - (k6 << 4);
    half8 p0, p1; peFrag(wb, p0, p1);
#pragma unroll
    for (int df = 0; df < 3; ++df) {
      const int f = k6 - df;
      if (f >= 0 && f <= 3) {
        f32x4 a = {0, 0, 0, 0};
        a = MFMA32(p0, bq0[f], a);
        a = MFMA32(p1, bq1[f], a);
        stripWrite(f, wb, a);
      }
    }
  }

  float zac[4] = {0, 0, 0, 0}, zmc[4] = {0, 0, 0, 0};
  f32x4 o[4][4];
#pragma unroll
  for (int f = 0; f < 4; ++f)
#pragma unroll
    for (int dc = 0; dc < 4; ++dc) o[f][dc] = f32x4{0, 0, 0, 0};

  for (int t = 0; t < 17; ++t) {
    const int g = g0 + t;
    const bool more = (t < 16);
    if (more) { issueKV(g + 1); issuePe(g + 2); }

    const int sK = (g & 1) * 2304;
    const int sV = 4608 + (g & 1) * 2560;
    const int bB = (g << 5) - 64 * w2;

    // K A-frags (shared by all m-frags)
    const half8 ak00 = *(const half8*)(lsh + sK + c * 72 + qd * 8);
    const half8 ak01 = *(const half8*)(lsh + sK + c * 72 + 32 + qd * 8);
    const half8 ak10 = *(const half8*)(lsh + sK + (16 + c) * 72 + qd * 8);
    const half8 ak11 = *(const half8*)(lsh + sK + (16 + c) * 72 + 32 + qd * 8);
    // V^T A-frags (shared)
    half4 av[8];
#pragma unroll
    for (int dc = 0; dc < 4; ++dc)
#pragma unroll
      for (int kg = 0; kg < 2; ++kg)
        av[dc * 2 + kg] = *(const half4*)(lsh + sV + (dc * 16 + c) * 40 + kg * 16 + qd * 4);

    // ---- per-frag S^T -> softmax (strips prewritten at t-1) -> PV ----
#pragma unroll
    for (int f = 0; f < 4; ++f) {
      f32x4 s0 = {0, 0, 0, 0}, s1 = {0, 0, 0, 0};
      s0 = MFMA32(ak00, bq0[f], s0); s0 = MFMA32(ak01, bq1[f], s0);
      s1 = MFMA32(ak10, bq0[f], s1); s1 = MFMA32(ak11, bq1[f], s1);

      const int base_f = bB - 16 * f;
      const half_t* stf = lsh + 23552 + (w2 * 4 + f) * 1536;
      const bool interior = (base_f >= 16 && base_f <= 2016);
      float pm0[4], pm1[4];
#pragma unroll
      for (int reg = 0; reg < 4; ++reg) {
        const int l0 = base_f + qd * 4 + reg - c;
        const int l1 = l0 + 16;
        const float b0 = (float)stf[(l0 & 63) * 24 + c];
        const float b1 = (float)stf[(l1 & 63) * 24 + c];
        float e0, e1;
        if (interior) { e0 = s0[reg] + b0; e1 = s1[reg] + b1; }
        else {
          e0 = (l0 >= 0 && l0 < kL) ? s0[reg] + b0 : -1e38f;
          e1 = (l1 >= 0 && l1 < kL) ? s1[reg] + b1 : -1e38f;
        }
        const float p0 = __builtin_amdgcn_exp2f(e0);
        const float p1 = __builtin_amdgcn_exp2f(e1);
        const float mk0 = fminf(fmaxf(((float)l0 + cvl) * 0.015625f + 1.0f, 0.0f), 1.0f);
        const float mk1 = fminf(fmaxf(((float)l1 + cvl) * 0.015625f + 1.0f, 0.0f), 1.0f);
        pm0[reg] = p0 * mk0; pm1[reg] = p1 * mk1;
        zac[f] += p0 + p1;
        zmc[f] += pm0[reg] + pm1[reg];
      }
      const half4 pb0h = { (half_t)pm0[0], (half_t)pm0[1], (half_t)pm0[2], (half_t)pm0[3] };
      const half4 pb1h = { (half_t)pm1[0], (half_t)pm1[1], (half_t)pm1[2], (half_t)pm1[3] };
#pragma unroll
      for (int dc = 0; dc < 4; ++dc) {
        o[f][dc] = MFMA16(av[dc * 2 + 0], pb0h, o[f][dc]);
        o[f][dc] = MFMA16(av[dc * 2 + 1], pb1h, o[f][dc]);
      }
    }

    // ---- bias windows for step t+1 (AFTER all strip reads; off critical path) ----
    if (more) {
      const int bBn = bB + 32;
#pragma unroll
      for (int k5 = 0; k5 < 5; ++k5) {
        const int wb = bBn + 16 - (k5 << 4);
        half8 p0, p1; peFrag(wb, p0, p1);
        if (k5 < 4) {
          f32x4 a = {0, 0, 0, 0};
          a = MFMA32(p0, bq0[k5], a);
          a = MFMA32(p1, bq1[k5], a);
          stripWrite(k5, wb, a);
        }
        if (k5 >= 1) {
          f32x4 a = {0, 0, 0, 0};
          a = MFMA32(p0, bq0[k5 - 1], a);
          a = MFMA32(p1, bq1[k5 - 1], a);
          stripWrite(k5 - 1, wb, a);
        }
      }
      commitKV(g + 1); commitPe(g + 2);
    }
    __syncthreads();
  }

  // ---- epilogue: O via LDS transpose + coalesced atomicAdd; z atomics ----
  float* Ow = (float*)smem + (size_t)w2 * 4352;   // [64 rows][stride 68] f32
#pragma unroll
  for (int f = 0; f < 4; ++f)
#pragma unroll
    for (int dc = 0; dc < 4; ++dc)
      *(f32x4*)(Ow + (16 * f + c) * 68 + dc * 16 + qd * 4) = o[f][dc];

#pragma unroll
  for (int f = 0; f < 4; ++f) {
    float a = zac[f], m = zmc[f];
    a += __shfl_xor(a, 16); a += __shfl_xor(a, 32);
    m += __shfl_xor(m, 16); m += __shfl_xor(m, 32);
    if (lane < 16) {
      const int row = bh * kM + m0 + 64 * w2 + 16 * f + c;
      atomicAdd(&zalA[row], a);
      atomicAdd(&zmA[row], m);
    }
  }
  const int rowbase = bh * kM + m0 + 64 * w2;
  for (int rr = 0; rr < 64; ++rr)
    atomicAdd(out + (size_t)(rowbase + rr) * kD + lane, Ow[rr * 68 + lane]);
}

// ---------- K3: normalize ----------
__global__ __launch_bounds__(256) void norm_kernel(const float* __restrict__ zalA,
    const float* __restrict__ zmA, float* __restrict__ out) {
  const int i = blockIdx.x * 256 + threadIdx.x;   // 262,144
  const int row = i >> 4, d4 = (i & 15) << 2;
  const float inv = 1.0f / (zmA[row] + 1e-8f * zalA[row]);
  float4* p = (float4*)(out + (size_t)row * 64 + d4);
  float4 v = *p;
  v.x *= inv; v.y *= inv; v.z *= inv; v.w *= inv;
  *p = v;
}

extern "C" void kernel_launch(void* const* d_in, const int* in_sizes, int n_in,
                              void* d_out, int out_size, void* d_ws, size_t ws_size,
                              hipStream_t stream) {
  (void)in_sizes; (void)n_in; (void)out_size; (void)ws_size;
  const float* q  = (const float*)d_in[0];
  const float* k  = (const float*)d_in[1];
  const float* v  = (const float*)d_in[2];
  const float* pe = (const float*)d_in[3];
  const float* cv = (const float*)d_in[4];
  half_t* ws = (half_t*)d_ws;   // needs ~23.8 MB
  float* out = (float*)d_out;
  float* zalA = (float*)(ws + WS_Z);
  float* zmA  = zalA + 16384;

  prep_kernel<<<4648, 256, 0, stream>>>(q, k, v, pe, ws, out);
  attn_kernel<<<512, 128, 0, stream>>>(ws, cv, out, zalA, zmA);
  norm_kernel<<<1024, 256, 0, stream>>>(zalA, zmA, out);
}

// Round 10
// 168.002 us; speedup vs baseline: 1.0711x; 1.0711x over previous
//
#include <hip/hip_runtime.h>

typedef _Float16 half_t;
typedef _Float16 half8 __attribute__((ext_vector_type(8)));
typedef _Float16 half4 __attribute__((ext_vector_type(4)));
typedef float f32x4 __attribute__((ext_vector_type(4)));

#define MFMA32(a, b, c) __builtin_amdgcn_mfma_f32_16x16x32_f16((a), (b), (c), 0, 0, 0)
#define MFMA16(a, b, c) __builtin_amdgcn_mfma_f32_16x16x16f16((a), (b), (c), 0, 0, 0)

static constexpr int kM  = 512;
static constexpr int kD  = 64;
static constexpr int kKL = 2560;
static constexpr int kL  = 2048;
// ws (halves): q_scaled | K [bh][k][d] | Vc chunked [bh][80][64][32] | peT [l][d] | z (f32)
static constexpr int WS_QS  = 0;                    // 1,048,576
static constexpr int WS_KB  = 1048576;              // 5,242,880
static constexpr int WS_VC  = WS_KB + 5242880;      // 5,242,880
static constexpr int WS_PET = WS_VC + 5242880;      // 131,072
static constexpr int WS_Z   = WS_PET + 131072;      // 2*16384 f32

// ---------- K1: q/k convert + V chunked-transpose + pe transpose + zero out/z ----------
__global__ __launch_bounds__(256) void prep_kernel(const float* __restrict__ q,
    const float* __restrict__ k, const float* __restrict__ v,
    const float* __restrict__ pe, half_t* __restrict__ ws, float* __restrict__ out) {
  __shared__ float ls[64 * 72];
  const int b = blockIdx.x, t = threadIdx.x;
  if (b < 3072) {
    const int i = b * 256 + t;
    const float QS = 0.125f * 1.4426950408889634f;  // 1/sqrt(64) * log2(e)
    const float* src; half_t* dst; float sc;
    if (i < 131072) { src = q + (size_t)i * 8; dst = ws + WS_QS + (size_t)i * 8; sc = QS; }
    else { const int j = i - 131072; src = k + (size_t)j * 8; dst = ws + WS_KB + (size_t)j * 8; sc = 1.0f; }
    const float4 a = ((const float4*)src)[0];
    const float4 bb = ((const float4*)src)[1];
    half_t tt[8];
    tt[0] = (half_t)(a.x * sc);  tt[1] = (half_t)(a.y * sc);
    tt[2] = (half_t)(a.z * sc);  tt[3] = (half_t)(a.w * sc);
    tt[4] = (half_t)(bb.x * sc); tt[5] = (half_t)(bb.y * sc);
    tt[6] = (half_t)(bb.z * sc); tt[7] = (half_t)(bb.w * sc);
    *(int4*)dst = *(int4*)tt;
    return;
  }
  if (b >= 4384) {
    if (b < 4640) {                       // zero d_out
      float4* o = (float4*)out;
      const int base = (b - 4384) * 1024 + t;
#pragma unroll
      for (int u = 0; u < 4; ++u) o[base + u * 256] = float4{0, 0, 0, 0};
    } else {                              // zero z
      float4* z = (float4*)((float*)(ws + WS_Z));
      const int base = (b - 4640) * 1024 + t;
#pragma unroll
      for (int u = 0; u < 4; ++u) z[base + u * 256] = float4{0, 0, 0, 0};
    }
    return;
  }
  const bool isV = (b < 4352);
  int bh = 0, kt = 0, b3 = 0;
  const float* src; int sstride;
  if (isV) {
    const int b2 = b - 3072;
    bh = b2 / 40; kt = b2 % 40;
    src = v + (size_t)(bh * 2560 + kt * 64) * 64; sstride = 64;
  } else {
    b3 = b - 4352;
    src = pe + (size_t)b3 * 64; sstride = 2048;
  }
  const int rr = t >> 4, cq = (t & 15) * 4;
#pragma unroll
  for (int p = 0; p < 4; ++p) {
    const float4 x = *(const float4*)(src + (size_t)(p * 16 + rr) * sstride + cq);
    *(float4*)(ls + (p * 16 + rr) * 72 + cq) = x;
  }
  __syncthreads();
  const int oc = t >> 2, ch = t & 3;
  half_t tmp[16];
#pragma unroll
  for (int i2 = 0; i2 < 16; ++i2) tmp[i2] = (half_t)ls[(ch * 16 + i2) * 72 + oc];
  half_t* o;
  if (isV) {
    o = ws + WS_VC + (size_t)bh * 163840 + ((kt << 1) + (ch >> 1)) * 2048 + oc * 32 + ((ch & 1) << 4);
  } else {
    o = ws + WS_PET + ((size_t)b3 * 64 + oc) * 64 + ch * 16;
  }
  ((int4*)o)[0] = ((int4*)tmp)[0];
  ((int4*)o)[1] = ((int4*)tmp)[1];
}

// ---------- K2: thin-wave high-TLP split-K attention ----------
// grid 1024 = 32bh x 4 m-blocks(128 rows) x 8 K-splits; block 256 (4 waves).
// Wave w owns rows m0+32w..+31 as 2 m-frags. 9 steps (tail split 5).
// LDS 39,936 B -> 4 blocks/CU x 4 waves = 16 waves/CU = 4 waves/SIMD: latency
// hiding via TLP (R6-R9 showed chain-shortening at 1 wave/SIMD is a dead end).
// K/Vc block-staged coalesced, double-buffered; PE bias A-frags from GLOBAL
// (R8/R9 A/B: equal cost to LDS ring; saves 23KB LDS = the 4th block/CU).
// Strips wave-private f16 [64][20]; windows for t+1 written after reads.
__global__ __launch_bounds__(256, 4) void attn_kernel(
    const half_t* __restrict__ ws, const float* __restrict__ cvp,
    float* __restrict__ out, float* __restrict__ zalA, float* __restrict__ zmA) {

  __shared__ __align__(16) char smem[39936];
  half_t* lsh = (half_t*)smem;

  const int tid  = threadIdx.x;
  const int lane = tid & 63;
  const int w    = tid >> 6;                    // wave 0..3
  const int c    = lane & 15;
  const int qd   = lane >> 4;

  const int id = blockIdx.x;                    // 1024
  const int bh = ((id & 7) << 2) | (id >> 8);   // XCD-aware
  const int mid = (id >> 3) & 31;
  const int mb = mid & 3, sp = mid >> 2;
  const int m0 = mb << 7;                       // 128 rows per block
  const int g0 = sp * 9;                        // chunks [g0, g0+tmax)
  const int tmax = (sp == 7) ? 5 : 9;           // 68 chunks total

  const float cvl = cvp[bh & 7] * 2048.0f - 2047.0f;  // mask = clamp((l+cvl)/64+1,0,1)

  const half_t* kb  = ws + WS_KB + (size_t)bh * (kKL * kD);
  const half_t* vcb = ws + WS_VC + (size_t)bh * (kKL * kD);
  const half_t* pet = ws + WS_PET;

  // Q B-frags for the wave's 2 m-frags (rows m0+32w+16f+c)
  half8 bq0[2], bq1[2];
#pragma unroll
  for (int f = 0; f < 2; ++f) {
    const half_t* qrow = ws + WS_QS + (size_t)(bh * kM + m0 + 32 * w + 16 * f + c) * kD;
    bq0[f] = *(const half8*)(qrow + qd * 8);
    bq1[f] = *(const half8*)(qrow + 32 + qd * 8);
  }

  // LDS (halves): K ring 2x2304 @0 | Vc ring 2x2560 @4608 | strips 8x1280 @9728
  int4 stgK, stgV;
  auto issueKV = [&](int gg) {
    const int r = tid >> 3, seg = tid & 7;
    int krow = m0 + (gg << 5) + r; if (krow > kKL - 1) krow = kKL - 1;
    stgK = *(const int4*)(kb + (size_t)krow * kD + seg * 8);
    int vch = (m0 >> 5) + gg; if (vch > 79) vch = 79;
    stgV = *(const int4*)(vcb + (size_t)vch * 2048 + tid * 8);
  };
  auto commitKV = [&](int gg) {
    const int sK = (gg & 1) * 2304;
    const int sV = 4608 + (gg & 1) * 2560;
    const int r = tid >> 3, seg = tid & 7;
    *(int4*)(lsh + sK + r * 72 + seg * 8) = stgK;
    const int d = tid >> 2, ks = (tid & 3) * 8;
    *(int4*)(lsh + sV + d * 40 + ks) = stgV;
  };
  auto stripWrite = [&](int f, int wb, const f32x4& a) {
    half_t* stf = lsh + 9728 + (w * 2 + f) * 1280;   // [64][20] f16
#pragma unroll
    for (int reg = 0; reg < 4; ++reg)
      stf[((wb + qd * 4 + reg) & 63) * 20 + c] = (half_t)a[reg];
  };
  auto peWindow = [&](int wb, f32x4& accf0, f32x4& accf1, bool dof0, bool dof1) {
    int l = wb + c; l = l < 0 ? 0 : (l > kL - 1 ? kL - 1 : l);
    const half8 p0 = *(const half8*)(pet + (size_t)l * kD + qd * 8);
    const half8 p1 = *(const half8*)(pet + (size_t)l * kD + 32 + qd * 8);
    if (dof0) { f32x4 a = {0,0,0,0}; a = MFMA32(p0, bq0[0], a); accf0 = MFMA32(p1, bq1[0], a); }
    if (dof1) { f32x4 a = {0,0,0,0}; a = MFMA32(p0, bq0[1], a); accf1 = MFMA32(p1, bq1[1], a); }
  };

  // ---- prime: K/V chunk g0 + 4 bias windows (coverage [B-48, B+31], B=32g0-32w) ----
  issueKV(g0);
  const int B0 = (g0 << 5) - 32 * w;
#pragma unroll
  for (int k4 = 0; k4 < 4; ++k4) {
    const int wb = B0 + 16 - (k4 << 4);
    f32x4 a0, a1;
    const bool d0 = (k4 <= 2), d1 = (k4 >= 1);
    peWindow(wb, a0, a1, d0, d1);
    if (d0) stripWrite(0, wb, a0);
    if (d1) stripWrite(1, wb, a1);
  }
  commitKV(g0);
  __syncthreads();

  float zac[2] = {0, 0}, zmc[2] = {0, 0};
  f32x4 o[2][4];
#pragma unroll
  for (int f = 0; f < 2; ++f)
#pragma unroll
    for (int dc = 0; dc < 4; ++dc) o[f][dc] = f32x4{0, 0, 0, 0};

  for (int t = 0; t < tmax; ++t) {
    const int g = g0 + t;
    const bool more = (t + 1 < tmax);
    if (more) issueKV(g + 1);

    const int sK = (g & 1) * 2304;
    const int sV = 4608 + (g & 1) * 2560;
    const int B = (g << 5) - 32 * w;             // base_f0

    // K A-frags (shared by both m-frags)
    const half8 ak00 = *(const half8*)(lsh + sK + c * 72 + qd * 8);
    const half8 ak01 = *(const half8*)(lsh + sK + c * 72 + 32 + qd * 8);
    const half8 ak10 = *(const half8*)(lsh + sK + (16 + c) * 72 + qd * 8);
    const half8 ak11 = *(const half8*)(lsh + sK + (16 + c) * 72 + 32 + qd * 8);

    // ---- per-frag: S^T -> softmax (strips pre-written) -> PV ----
#pragma unroll
    for (int f = 0; f < 2; ++f) {
      f32x4 s0 = {0, 0, 0, 0}, s1 = {0, 0, 0, 0};
      s0 = MFMA32(ak00, bq0[f], s0); s0 = MFMA32(ak01, bq1[f], s0);
      s1 = MFMA32(ak10, bq0[f], s1); s1 = MFMA32(ak11, bq1[f], s1);

      const int base_f = B - 16 * f;
      const half_t* stf = lsh + 9728 + (w * 2 + f) * 1280;
      const bool interior = (base_f >= 16 && base_f <= 2016);
      float pm0[4], pm1[4];
#pragma unroll
      for (int reg = 0; reg < 4; ++reg) {
        const int l0 = base_f + qd * 4 + reg - c;
        const int l1 = l0 + 16;
        const float b0 = (float)stf[(l0 & 63) * 20 + c];
        const float b1 = (float)stf[(l1 & 63) * 20 + c];
        float e0, e1;
        if (interior) { e0 = s0[reg] + b0; e1 = s1[reg] + b1; }
        else {
          e0 = (l0 >= 0 && l0 < kL) ? s0[reg] + b0 : -1e38f;
          e1 = (l1 >= 0 && l1 < kL) ? s1[reg] + b1 : -1e38f;
        }
        const float p0 = __builtin_amdgcn_exp2f(e0);
        const float p1 = __builtin_amdgcn_exp2f(e1);
        const float mk0 = fminf(fmaxf(((float)l0 + cvl) * 0.015625f + 1.0f, 0.0f), 1.0f);
        const float mk1 = fminf(fmaxf(((float)l1 + cvl) * 0.015625f + 1.0f, 0.0f), 1.0f);
        pm0[reg] = p0 * mk0; pm1[reg] = p1 * mk1;
        zac[f] += p0 + p1;
        zmc[f] += pm0[reg] + pm1[reg];
      }
      const half4 pb0h = { (half_t)pm0[0], (half_t)pm0[1], (half_t)pm0[2], (half_t)pm0[3] };
      const half4 pb1h = { (half_t)pm1[0], (half_t)pm1[1], (half_t)pm1[2], (half_t)pm1[3] };
#pragma unroll
      for (int dc = 0; dc < 4; ++dc) {
        const half4 av0 = *(const half4*)(lsh + sV + (dc * 16 + c) * 40 + qd * 4);
        const half4 av1 = *(const half4*)(lsh + sV + (dc * 16 + c) * 40 + 16 + qd * 4);
        o[f][dc] = MFMA16(av0, pb0h, o[f][dc]);
        o[f][dc] = MFMA16(av1, pb1h, o[f][dc]);
      }
    }

    // ---- bias windows for t+1 (after strip reads): wb = B+48, B+32, B+16 ----
    if (more) {
#pragma unroll
      for (int k3 = 0; k3 < 3; ++k3) {
        const int wb = B + 48 - (k3 << 4);
        f32x4 a0, a1;
        const bool d0 = (k3 <= 1), d1 = (k3 >= 1);
        peWindow(wb, a0, a1, d0, d1);
        if (d0) stripWrite(0, wb, a0);
        if (d1) stripWrite(1, wb, a1);
      }
      commitKV(g + 1);
    }
    __syncthreads();
  }

  // ---- epilogue: z atomics + O via LDS transpose + coalesced atomicAdd ----
  __syncthreads();                              // protect shared K/V from overlay
  float* Ow = (float*)smem + (size_t)w * 2176;  // [32 rows][stride 68] f32
#pragma unroll
  for (int f = 0; f < 2; ++f)
#pragma unroll
    for (int dc = 0; dc < 4; ++dc)
      *(f32x4*)(Ow + (16 * f + c) * 68 + dc * 16 + qd * 4) = o[f][dc];

#pragma unroll
  for (int f = 0; f < 2; ++f) {
    float a = zac[f], m = zmc[f];
    a += __shfl_xor(a, 16); a += __shfl_xor(a, 32);
    m += __shfl_xor(m, 16); m += __shfl_xor(m, 32);
    if (lane < 16) {
      const int row = bh * kM + m0 + 32 * w + 16 * f + c;
      atomicAdd(&zalA[row], a);
      atomicAdd(&zmA[row], m);
    }
  }
  const int rowbase = bh * kM + m0 + 32 * w;
  for (int rr = 0; rr < 32; ++rr)
    atomicAdd(out + (size_t)(rowbase + rr) * kD + lane, Ow[rr * 68 + lane]);
}

// ---------- K3: normalize ----------
__global__ __launch_bounds__(256) void norm_kernel(const float* __restrict__ zalA,
    const float* __restrict__ zmA, float* __restrict__ out) {
  const int i = blockIdx.x * 256 + threadIdx.x;   // 262,144
  const int row = i >> 4, d4 = (i & 15) << 2;
  const float inv = 1.0f / (zmA[row] + 1e-8f * zalA[row]);
  float4* p = (float4*)(out + (size_t)row * 64 + d4);
  float4 v = *p;
  v.x *= inv; v.y *= inv; v.z *= inv; v.w *= inv;
  *p = v;
}

extern "C" void kernel_launch(void* const* d_in, const int* in_sizes, int n_in,
                              void* d_out, int out_size, void* d_ws, size_t ws_size,
                              hipStream_t stream) {
  (void)in_sizes; (void)n_in; (void)out_size; (void)ws_size;
  const float* q  = (const float*)d_in[0];
  const float* k  = (const float*)d_in[1];
  const float* v  = (const float*)d_in[2];
  const float* pe = (const float*)d_in[3];
  const float* cv = (const float*)d_in[4];
  half_t* ws = (half_t*)d_ws;   // needs ~23.6 MB
  float* out = (float*)d_out;
  float* zalA = (float*)(ws + WS_Z);
  float* zmA  = zalA + 16384;

  prep_kernel<<<4648, 256, 0, stream>>>(q, k, v, pe, ws, out);
  attn_kernel<<<1024, 256, 0, stream>>>(ws, cv, out, zalA, zmA);
  norm_kernel<<<1024, 256, 0, stream>>>(zalA, zmA, out);
}

// Round 11
// 152.735 us; speedup vs baseline: 1.1781x; 1.1000x over previous
//
#include <hip/hip_runtime.h>

typedef _Float16 half_t;
typedef _Float16 half8 __attribute__((ext_vector_type(8)));
typedef _Float16 half4 __attribute__((ext_vector_type(4)));
typedef float f32x4 __attribute__((ext_vector_type(4)));

#define MFMA32(a, b, c) __builtin_amdgcn_mfma_f32_16x16x32_f16((a), (b), (c), 0, 0, 0)
#define MFMA16(a, b, c) __builtin_amdgcn_mfma_f32_16x16x16f16((a), (b), (c), 0, 0, 0)

static constexpr int kM  = 512;
static constexpr int kD  = 64;
static constexpr int kKL = 2560;
static constexpr int kL  = 2048;
// ws (halves): q_scaled | K [bh][k][d] | Vc chunked [bh][80][64][32] | peT [l][d] | z (f32)
static constexpr int WS_QS  = 0;                    // 1,048,576
static constexpr int WS_KB  = 1048576;              // 5,242,880
static constexpr int WS_VC  = WS_KB + 5242880;      // 5,242,880
static constexpr int WS_PET = WS_VC + 5242880;      // 131,072
static constexpr int WS_Z   = WS_PET + 131072;      // 2*16384 f32

// ---------- K1: q/k convert + V chunked-transpose + pe transpose + zero out/z ----------
__global__ __launch_bounds__(256) void prep_kernel(const float* __restrict__ q,
    const float* __restrict__ k, const float* __restrict__ v,
    const float* __restrict__ pe, half_t* __restrict__ ws, float* __restrict__ out) {
  __shared__ float ls[64 * 72];
  const int b = blockIdx.x, t = threadIdx.x;
  if (b < 3072) {
    const int i = b * 256 + t;
    const float QS = 0.125f * 1.4426950408889634f;  // 1/sqrt(64) * log2(e)
    const float* src; half_t* dst; float sc;
    if (i < 131072) { src = q + (size_t)i * 8; dst = ws + WS_QS + (size_t)i * 8; sc = QS; }
    else { const int j = i - 131072; src = k + (size_t)j * 8; dst = ws + WS_KB + (size_t)j * 8; sc = 1.0f; }
    const float4 a = ((const float4*)src)[0];
    const float4 bb = ((const float4*)src)[1];
    half_t tt[8];
    tt[0] = (half_t)(a.x * sc);  tt[1] = (half_t)(a.y * sc);
    tt[2] = (half_t)(a.z * sc);  tt[3] = (half_t)(a.w * sc);
    tt[4] = (half_t)(bb.x * sc); tt[5] = (half_t)(bb.y * sc);
    tt[6] = (half_t)(bb.z * sc); tt[7] = (half_t)(bb.w * sc);
    *(int4*)dst = *(int4*)tt;
    return;
  }
  if (b >= 4384) {
    if (b < 4640) {                       // zero d_out
      float4* o = (float4*)out;
      const int base = (b - 4384) * 1024 + t;
#pragma unroll
      for (int u = 0; u < 4; ++u) o[base + u * 256] = float4{0, 0, 0, 0};
    } else {                              // zero z
      float4* z = (float4*)((float*)(ws + WS_Z));
      const int base = (b - 4640) * 1024 + t;
#pragma unroll
      for (int u = 0; u < 4; ++u) z[base + u * 256] = float4{0, 0, 0, 0};
    }
    return;
  }
  const bool isV = (b < 4352);
  int bh = 0, kt = 0, b3 = 0;
  const float* src; int sstride;
  if (isV) {
    const int b2 = b - 3072;
    bh = b2 / 40; kt = b2 % 40;
    src = v + (size_t)(bh * 2560 + kt * 64) * 64; sstride = 64;
  } else {
    b3 = b - 4352;
    src = pe + (size_t)b3 * 64; sstride = 2048;
  }
  const int rr = t >> 4, cq = (t & 15) * 4;
#pragma unroll
  for (int p = 0; p < 4; ++p) {
    const float4 x = *(const float4*)(src + (size_t)(p * 16 + rr) * sstride + cq);
    *(float4*)(ls + (p * 16 + rr) * 72 + cq) = x;
  }
  __syncthreads();
  const int oc = t >> 2, ch = t & 3;
  half_t tmp[16];
#pragma unroll
  for (int i2 = 0; i2 < 16; ++i2) tmp[i2] = (half_t)ls[(ch * 16 + i2) * 72 + oc];
  half_t* o;
  if (isV) {
    o = ws + WS_VC + (size_t)bh * 163840 + ((kt << 1) + (ch >> 1)) * 2048 + oc * 32 + ((ch & 1) << 4);
  } else {
    o = ws + WS_PET + ((size_t)b3 * 64 + oc) * 64 + ch * 16;
  }
  ((int4*)o)[0] = ((int4*)tmp)[0];
  ((int4*)o)[1] = ((int4*)tmp)[1];
}

// ---------- K2: thin-wave high-TLP split-K attention ----------
// grid 1024 = 32bh x 4 m-blocks(128 rows) x 8 K-splits; block 256 (4 waves).
// R10 RETRO: __launch_bounds__(256,4) forced VGPR=64 -> heavy scratch spill
// (WRITE_SIZE 97MB, hbm 1.25TB/s of spill traffic) which masked the TLP test.
// (256,3): VGPR budget 170 (live set ~130, no spill), LDS 39.9KB -> 3 blocks/CU
// by VGPR, 3 waves/SIMD. Single-variable change vs R10.
__global__ __launch_bounds__(256, 3) void attn_kernel(
    const half_t* __restrict__ ws, const float* __restrict__ cvp,
    float* __restrict__ out, float* __restrict__ zalA, float* __restrict__ zmA) {

  __shared__ __align__(16) char smem[39936];
  half_t* lsh = (half_t*)smem;

  const int tid  = threadIdx.x;
  const int lane = tid & 63;
  const int w    = tid >> 6;                    // wave 0..3
  const int c    = lane & 15;
  const int qd   = lane >> 4;

  const int id = blockIdx.x;                    // 1024
  const int bh = ((id & 7) << 2) | (id >> 8);   // XCD-aware
  const int mid = (id >> 3) & 31;
  const int mb = mid & 3, sp = mid >> 2;
  const int m0 = mb << 7;                       // 128 rows per block
  const int g0 = sp * 9;                        // chunks [g0, g0+tmax)
  const int tmax = (sp == 7) ? 5 : 9;           // 68 chunks total

  const float cvl = cvp[bh & 7] * 2048.0f - 2047.0f;  // mask = clamp((l+cvl)/64+1,0,1)

  const half_t* kb  = ws + WS_KB + (size_t)bh * (kKL * kD);
  const half_t* vcb = ws + WS_VC + (size_t)bh * (kKL * kD);
  const half_t* pet = ws + WS_PET;

  // Q B-frags for the wave's 2 m-frags (rows m0+32w+16f+c)
  half8 bq0[2], bq1[2];
#pragma unroll
  for (int f = 0; f < 2; ++f) {
    const half_t* qrow = ws + WS_QS + (size_t)(bh * kM + m0 + 32 * w + 16 * f + c) * kD;
    bq0[f] = *(const half8*)(qrow + qd * 8);
    bq1[f] = *(const half8*)(qrow + 32 + qd * 8);
  }

  // LDS (halves): K ring 2x2304 @0 | Vc ring 2x2560 @4608 | strips 8x1280 @9728
  int4 stgK, stgV;
  auto issueKV = [&](int gg) {
    const int r = tid >> 3, seg = tid & 7;
    int krow = m0 + (gg << 5) + r; if (krow > kKL - 1) krow = kKL - 1;
    stgK = *(const int4*)(kb + (size_t)krow * kD + seg * 8);
    int vch = (m0 >> 5) + gg; if (vch > 79) vch = 79;
    stgV = *(const int4*)(vcb + (size_t)vch * 2048 + tid * 8);
  };
  auto commitKV = [&](int gg) {
    const int sK = (gg & 1) * 2304;
    const int sV = 4608 + (gg & 1) * 2560;
    const int r = tid >> 3, seg = tid & 7;
    *(int4*)(lsh + sK + r * 72 + seg * 8) = stgK;
    const int d = tid >> 2, ks = (tid & 3) * 8;
    *(int4*)(lsh + sV + d * 40 + ks) = stgV;
  };
  auto stripWrite = [&](int f, int wb, const f32x4& a) {
    half_t* stf = lsh + 9728 + (w * 2 + f) * 1280;   // [64][20] f16
#pragma unroll
    for (int reg = 0; reg < 4; ++reg)
      stf[((wb + qd * 4 + reg) & 63) * 20 + c] = (half_t)a[reg];
  };
  auto peWindow = [&](int wb, f32x4& accf0, f32x4& accf1, bool dof0, bool dof1) {
    int l = wb + c; l = l < 0 ? 0 : (l > kL - 1 ? kL - 1 : l);
    const half8 p0 = *(const half8*)(pet + (size_t)l * kD + qd * 8);
    const half8 p1 = *(const half8*)(pet + (size_t)l * kD + 32 + qd * 8);
    if (dof0) { f32x4 a = {0,0,0,0}; a = MFMA32(p0, bq0[0], a); accf0 = MFMA32(p1, bq1[0], a); }
    if (dof1) { f32x4 a = {0,0,0,0}; a = MFMA32(p0, bq0[1], a); accf1 = MFMA32(p1, bq1[1], a); }
  };

  // ---- prime: K/V chunk g0 + 4 bias windows (coverage [B-48, B+31], B=32g0-32w) ----
  issueKV(g0);
  const int B0 = (g0 << 5) - 32 * w;
#pragma unroll
  for (int k4 = 0; k4 < 4; ++k4) {
    const int wb = B0 + 16 - (k4 << 4);
    f32x4 a0, a1;
    const bool d0 = (k4 <= 2), d1 = (k4 >= 1);
    peWindow(wb, a0, a1, d0, d1);
    if (d0) stripWrite(0, wb, a0);
    if (d1) stripWrite(1, wb, a1);
  }
  commitKV(g0);
  __syncthreads();

  float zac[2] = {0, 0}, zmc[2] = {0, 0};
  f32x4 o[2][4];
#pragma unroll
  for (int f = 0; f < 2; ++f)
#pragma unroll
    for (int dc = 0; dc < 4; ++dc) o[f][dc] = f32x4{0, 0, 0, 0};

  for (int t = 0; t < tmax; ++t) {
    const int g = g0 + t;
    const bool more = (t + 1 < tmax);
    if (more) issueKV(g + 1);

    const int sK = (g & 1) * 2304;
    const int sV = 4608 + (g & 1) * 2560;
    const int B = (g << 5) - 32 * w;             // base_f0

    // K A-frags (shared by both m-frags)
    const half8 ak00 = *(const half8*)(lsh + sK + c * 72 + qd * 8);
    const half8 ak01 = *(const half8*)(lsh + sK + c * 72 + 32 + qd * 8);
    const half8 ak10 = *(const half8*)(lsh + sK + (16 + c) * 72 + qd * 8);
    const half8 ak11 = *(const half8*)(lsh + sK + (16 + c) * 72 + 32 + qd * 8);

    // ---- per-frag: S^T -> softmax (strips pre-written) -> PV ----
#pragma unroll
    for (int f = 0; f < 2; ++f) {
      f32x4 s0 = {0, 0, 0, 0}, s1 = {0, 0, 0, 0};
      s0 = MFMA32(ak00, bq0[f], s0); s0 = MFMA32(ak01, bq1[f], s0);
      s1 = MFMA32(ak10, bq0[f], s1); s1 = MFMA32(ak11, bq1[f], s1);

      const int base_f = B - 16 * f;
      const half_t* stf = lsh + 9728 + (w * 2 + f) * 1280;
      const bool interior = (base_f >= 16 && base_f <= 2016);
      float pm0[4], pm1[4];
#pragma unroll
      for (int reg = 0; reg < 4; ++reg) {
        const int l0 = base_f + qd * 4 + reg - c;
        const int l1 = l0 + 16;
        const float b0 = (float)stf[(l0 & 63) * 20 + c];
        const float b1 = (float)stf[(l1 & 63) * 20 + c];
        float e0, e1;
        if (interior) { e0 = s0[reg] + b0; e1 = s1[reg] + b1; }
        else {
          e0 = (l0 >= 0 && l0 < kL) ? s0[reg] + b0 : -1e38f;
          e1 = (l1 >= 0 && l1 < kL) ? s1[reg] + b1 : -1e38f;
        }
        const float p0 = __builtin_amdgcn_exp2f(e0);
        const float p1 = __builtin_amdgcn_exp2f(e1);
        const float mk0 = fminf(fmaxf(((float)l0 + cvl) * 0.015625f + 1.0f, 0.0f), 1.0f);
        const float mk1 = fminf(fmaxf(((float)l1 + cvl) * 0.015625f + 1.0f, 0.0f), 1.0f);
        pm0[reg] = p0 * mk0; pm1[reg] = p1 * mk1;
        zac[f] += p0 + p1;
        zmc[f] += pm0[reg] + pm1[reg];
      }
      const half4 pb0h = { (half_t)pm0[0], (half_t)pm0[1], (half_t)pm0[2], (half_t)pm0[3] };
      const half4 pb1h = { (half_t)pm1[0], (half_t)pm1[1], (half_t)pm1[2], (half_t)pm1[3] };
#pragma unroll
      for (int dc = 0; dc < 4; ++dc) {
        const half4 av0 = *(const half4*)(lsh + sV + (dc * 16 + c) * 40 + qd * 4);
        const half4 av1 = *(const half4*)(lsh + sV + (dc * 16 + c) * 40 + 16 + qd * 4);
        o[f][dc] = MFMA16(av0, pb0h, o[f][dc]);
        o[f][dc] = MFMA16(av1, pb1h, o[f][dc]);
      }
    }

    // ---- bias windows for t+1 (after strip reads): wb = B+48, B+32, B+16 ----
    if (more) {
#pragma unroll
      for (int k3 = 0; k3 < 3; ++k3) {
        const int wb = B + 48 - (k3 << 4);
        f32x4 a0, a1;
        const bool d0 = (k3 <= 1), d1 = (k3 >= 1);
        peWindow(wb, a0, a1, d0, d1);
        if (d0) stripWrite(0, wb, a0);
        if (d1) stripWrite(1, wb, a1);
      }
      commitKV(g + 1);
    }
    __syncthreads();
  }

  // ---- epilogue: z atomics + O via LDS transpose + coalesced atomicAdd ----
  __syncthreads();                              // protect shared K/V from overlay
  float* Ow = (float*)smem + (size_t)w * 2176;  // [32 rows][stride 68] f32
#pragma unroll
  for (int f = 0; f < 2; ++f)
#pragma unroll
    for (int dc = 0; dc < 4; ++dc)
      *(f32x4*)(Ow + (16 * f + c) * 68 + dc * 16 + qd * 4) = o[f][dc];

#pragma unroll
  for (int f = 0; f < 2; ++f) {
    float a = zac[f], m = zmc[f];
    a += __shfl_xor(a, 16); a += __shfl_xor(a, 32);
    m += __shfl_xor(m, 16); m += __shfl_xor(m, 32);
    if (lane < 16) {
      const int row = bh * kM + m0 + 32 * w + 16 * f + c;
      atomicAdd(&zalA[row], a);
      atomicAdd(&zmA[row], m);
    }
  }
  const int rowbase = bh * kM + m0 + 32 * w;
  for (int rr = 0; rr < 32; ++rr)
    atomicAdd(out + (size_t)(rowbase + rr) * kD + lane, Ow[rr * 68 + lane]);
}

// ---------- K3: normalize ----------
__global__ __launch_bounds__(256) void norm_kernel(const float* __restrict__ zalA,
    const float* __restrict__ zmA, float* __restrict__ out) {
  const int i = blockIdx.x * 256 + threadIdx.x;   // 262,144
  const int row = i >> 4, d4 = (i & 15) << 2;
  const float inv = 1.0f / (zmA[row] + 1e-8f * zalA[row]);
  float4* p = (float4*)(out + (size_t)row * 64 + d4);
  float4 v = *p;
  v.x *= inv; v.y *= inv; v.z *= inv; v.w *= inv;
  *p = v;
}

extern "C" void kernel_launch(void* const* d_in, const int* in_sizes, int n_in,
                              void* d_out, int out_size, void* d_ws, size_t ws_size,
                              hipStream_t stream) {
  (void)in_sizes; (void)n_in; (void)out_size; (void)ws_size;
  const float* q  = (const float*)d_in[0];
  const float* k  = (const float*)d_in[1];
  const float* v  = (const float*)d_in[2];
  const float* pe = (const float*)d_in[3];
  const float* cv = (const float*)d_in[4];
  half_t* ws = (half_t*)d_ws;   // needs ~23.6 MB
  float* out = (float*)d_out;
  float* zalA = (float*)(ws + WS_Z);
  float* zmA  = zalA + 16384;

  prep_kernel<<<4648, 256, 0, stream>>>(q, k, v, pe, ws, out);
  attn_kernel<<<1024, 256, 0, stream>>>(ws, cv, out, zalA, zmA);
  norm_kernel<<<1024, 256, 0, stream>>>(zalA, zmA, out);
}